// Round 8
// baseline (1379.278 us; speedup 1.0000x reference)
//
#include <hip/hip_runtime.h>
#include <hip/hip_bf16.h>
#include <math.h>

typedef __bf16 bf16x8 __attribute__((ext_vector_type(8)));
typedef float  f32x4  __attribute__((ext_vector_type(4)));
typedef __hip_bfloat16 bf16;

#define DIM  1024
#define MLPD 4096
#define NB   4
#define SEQ  2048
#define ROWS (NB * SEQ) /* 8192 */

__device__ __forceinline__ void gload_lds16(const void* g, void* l) {
  __builtin_amdgcn_global_load_lds(
      (__attribute__((address_space(1))) void*)(g),
      (__attribute__((address_space(3))) void*)(l), 16, 0, 0);
}

__device__ __forceinline__ void bar() {
  asm volatile("" ::: "memory");
  __builtin_amdgcn_s_barrier();
  asm volatile("" ::: "memory");
}

template <int N>
__device__ __forceinline__ void vmw() {
  asm volatile("s_waitcnt vmcnt(%0)" ::"n"(N) : "memory");
}

__device__ __forceinline__ bf16 to_bf16(float v) { return __float2bfloat16(v); }
__device__ __forceinline__ bf16 to_bf16(bf16 v)  { return v; }

// ---------------------------------------------------------------------------
// 128x128 GEMM, BK=32, 4 waves (2x2), 2x16KiB LDS double-buffer (32 KiB)
// -> 5 blocks/CU (160 KiB exactly; VGPR ~60 << 409 cap), depth-1 prefetch
// with vmcnt(0)+barrier per tile (r6 schedule).
// LDS geometry (r7, HW-verified 0 bank conflicts): per operand 64 row-pairs
// x 128B; 16B slot s = ((row&1)*4 + kchunk) ^ ((row>>1)&7). Read addr folds
// to per-thread base + m*1024. Staging keeps LINEAR gload_lds dests; the
// per-lane global SOURCE applies the inverse swizzle (G21 involution):
// t=wave*128+lane; r2=t>>3; u=(t&7)^(r2&7); row=2*r2+(u>>2); kc=u&3.
// EPI: 0=+bias->bf16 | 2=+resid->fp32 | 3=+bias,gelu->bf16
//      4=+bias+resid->fp32 | 5=*scale->bf16
// Requires: M%128==0, N%128==0, K%64==0 (NT even), gx%8==0, gy%8==0.
// ---------------------------------------------------------------------------
template <int EPI>
__global__ __launch_bounds__(256, 5) void gemm128(
    const bf16* __restrict__ A,  long aBatch, int lda,
    const bf16* __restrict__ Bt, long bBatch, int ldb,
    void* __restrict__ Cout,     long cBatch, int ldc,
    const float* __restrict__ bias,
    const float* __restrict__ resid, long rBatch, int ldr,
    int K, float scale)
{
  __shared__ char smem[2][16384];

  // ---- block swizzle: XCD chunking over 8x8 super-tile order
  const int gx = gridDim.x, gy = gridDim.y;
  const int n = gx * gy * gridDim.z;
  const int f = blockIdx.x + gx * (blockIdx.y + gy * blockIdx.z);
  const int o = (f & 7) * (n >> 3) + (f >> 3);   // bijective, n%8==0
  const int sx = gx >> 3;
  int st = o >> 6;
  const int w = o & 63;
  const int spz = sx * (gy >> 3);
  const int bz = st / spz; st -= bz * spz;
  const int sty = st / sx, stx = st - sty * sx;
  const int by = sty * 8 + (w >> 3), bx = stx * 8 + (w & 7);

  const long rowBase = (long)by * 128;
  const long colBase = (long)bx * 128;
  const long ldaB = (long)lda * 2, ldbB = (long)ldb * 2;
  const char* Ag = (const char*)(A + bz * aBatch + rowBase * lda);
  const char* Bg = (const char*)(Bt + bz * bBatch + colBase * ldb);

  const int tid  = threadIdx.x;
  const int lane = tid & 63;
  const int wave = tid >> 6;
  const int wm = wave >> 1, wn = wave & 1;   // 2x2 wave grid, 64x64 each
  const int fr = lane & 15, fq = lane >> 4;

  // fragment read bases: row-pair geometry, XOR folded into lane constants
  const int fh = fr >> 1;
  const int sA = (((fr & 1) << 2) | fq) ^ fh;
  const int laneRd = fh * 128 + sA * 16;
  const int abase = wm * 4096 + laneRd;
  const int bbase = 8192 + wn * 4096 + laneRd;

  // staging: linear dest, inverse-swizzled per-lane source
  const int t0   = wave * 128 + lane;
  const int r2   = t0 >> 3;
  const int u0   = (t0 & 7) ^ (r2 & 7);
  const int row0 = r2 * 2 + (u0 >> 2);
  const int kc0  = u0 & 3;
  const char* aSrc0 = Ag + (long)row0 * ldaB + kc0 * 16;
  const char* aSrc1 = aSrc0 + 16 * ldaB;   // t0+64 => row+16, same kchunk
  const char* bSrc0 = Bg + (long)row0 * ldbB + kc0 * 16;
  const char* bSrc1 = bSrc0 + 16 * ldbB;
  const int doff = wave * 2048 + lane * 16;

  const int NT = K >> 5;
  f32x4 acc[4][4] = {};

#define STAGE(WB)                                                              \
  do {                                                                         \
    gload_lds16(aSrc0, &smem[WB][doff]);                                       \
    gload_lds16(aSrc1, &smem[WB][doff + 1024]);                                \
    gload_lds16(bSrc0, &smem[WB][8192 + doff]);                                \
    gload_lds16(bSrc1, &smem[WB][8192 + doff + 1024]);                         \
    aSrc0 += 64; aSrc1 += 64; bSrc0 += 64; bSrc1 += 64;                        \
  } while (0)

#define READMM(RB)                                                             \
  do {                                                                         \
    const char* _r = &smem[RB][0];                                             \
    bf16x8 av[4], bv[4];                                                       \
    _Pragma("unroll") for (int m = 0; m < 4; ++m)                              \
      av[m] = *(const bf16x8*)(_r + abase + m * 1024);                         \
    _Pragma("unroll") for (int nn = 0; nn < 4; ++nn)                           \
      bv[nn] = *(const bf16x8*)(_r + bbase + nn * 1024);                       \
    __builtin_amdgcn_s_setprio(1);                                             \
    _Pragma("unroll") for (int m = 0; m < 4; ++m)                              \
      _Pragma("unroll") for (int nn = 0; nn < 4; ++nn)                         \
        acc[m][nn] = __builtin_amdgcn_mfma_f32_16x16x32_bf16(                  \
            av[m], bv[nn], acc[m][nn], 0, 0, 0);                               \
    __builtin_amdgcn_s_setprio(0);                                             \
  } while (0)

  // prologue: tile 0 -> buf0
  STAGE(0);
  vmw<0>(); bar();

  for (int t = 0; t < NT; t += 2) {
    STAGE(1);                   // tile t+1 (NT even => always valid)
    READMM(0);                  // tile t
    vmw<0>(); bar();
    if (t + 2 < NT) STAGE(0);   // tile t+2
    READMM(1);                  // tile t+1
    vmw<0>(); bar();
  }

#undef STAGE
#undef READMM

  // Epilogue (C/D mapping: col = ..+fr, row = ..+fq*4+e) — r1-verified
#pragma unroll
  for (int m = 0; m < 4; ++m) {
#pragma unroll
    for (int nn = 0; nn < 4; ++nn) {
      const long col = colBase + wn * 64 + nn * 16 + fr;
#pragma unroll
      for (int e = 0; e < 4; ++e) {
        const long r = rowBase + wm * 64 + m * 16 + fq * 4 + e;
        float v = acc[m][nn][e];
        if constexpr (EPI == 0) {
          v += bias[col];
          ((bf16*)Cout)[bz * cBatch + r * ldc + col] = __float2bfloat16(v);
        } else if constexpr (EPI == 2) {
          v += resid[bz * rBatch + r * ldr + col];
          ((float*)Cout)[bz * cBatch + r * ldc + col] = v;
        } else if constexpr (EPI == 3) {
          v += bias[col];
          const float gl = 0.5f * v * (1.0f + erff(v * 0.70710678118654752f));
          ((bf16*)Cout)[bz * cBatch + r * ldc + col] = __float2bfloat16(gl);
        } else if constexpr (EPI == 4) {
          v += bias[col] + resid[r * (long)ldr + col];
          ((float*)Cout)[bz * cBatch + r * ldc + col] = v;
        } else {  // 5
          ((bf16*)Cout)[bz * cBatch + r * ldc + col] = __float2bfloat16(v * scale);
        }
      }
    }
  }
}

// ---------------------------------------------------------------------------
// LayerNorm over DIM=1024, one block per row, fp32 in -> bf16 out
// ---------------------------------------------------------------------------
__global__ __launch_bounds__(256) void ln_kernel(
    const float* __restrict__ x, const float* __restrict__ gamma,
    const float* __restrict__ beta, bf16* __restrict__ out)
{
  const long row = blockIdx.x;
  const float4 v = ((const float4*)(x + row * DIM))[threadIdx.x];
  float s  = v.x + v.y + v.z + v.w;
  float ss = v.x * v.x + v.y * v.y + v.z * v.z + v.w * v.w;
  const int lane = threadIdx.x & 63, wave = threadIdx.x >> 6;
#pragma unroll
  for (int o = 32; o; o >>= 1) { s += __shfl_xor(s, o); ss += __shfl_xor(ss, o); }
  __shared__ float rs[4], rss[4];
  if (lane == 0) { rs[wave] = s; rss[wave] = ss; }
  __syncthreads();
  s  = rs[0] + rs[1] + rs[2] + rs[3];
  ss = rss[0] + rss[1] + rss[2] + rss[3];
  const float mean = s * (1.0f / DIM);
  const float var  = ss * (1.0f / DIM) - mean * mean;
  const float rstd = rsqrtf(var + 1e-5f);
  const float4 g = ((const float4*)gamma)[threadIdx.x];
  const float4 b = ((const float4*)beta)[threadIdx.x];
  union { bf16 h[4]; uint2 u; } pk;
  pk.h[0] = __float2bfloat16(g.x * (v.x - mean) * rstd + b.x);
  pk.h[1] = __float2bfloat16(g.y * (v.y - mean) * rstd + b.y);
  pk.h[2] = __float2bfloat16(g.z * (v.z - mean) * rstd + b.z);
  pk.h[3] = __float2bfloat16(g.w * (v.w - mean) * rstd + b.w);
  ((uint2*)(out + row * DIM))[threadIdx.x] = pk.u;
}

// ---------------------------------------------------------------------------
// Row softmax over SEQ=2048 bf16 scores, in-place bf16 out (row stride SEQ)
// ---------------------------------------------------------------------------
__global__ __launch_bounds__(256) void softmax_kernel(bf16* __restrict__ scores)
{
  const long row = blockIdx.x;
  bf16* rp = scores + row * (long)SEQ;
  union { bf16 h[8]; uint4 u; } in;
  in.u = ((const uint4*)rp)[threadIdx.x];
  float f[8];
#pragma unroll
  for (int j = 0; j < 8; ++j) f[j] = __bfloat162float(in.h[j]);
  const int lane = threadIdx.x & 63, wave = threadIdx.x >> 6;
  float mx = f[0];
#pragma unroll
  for (int j = 1; j < 8; ++j) mx = fmaxf(mx, f[j]);
#pragma unroll
  for (int o = 32; o; o >>= 1) mx = fmaxf(mx, __shfl_xor(mx, o));
  __shared__ float rm[4], rsum[4];
  if (lane == 0) rm[wave] = mx;
  __syncthreads();
  mx = fmaxf(fmaxf(rm[0], rm[1]), fmaxf(rm[2], rm[3]));
  float sum = 0.0f;
#pragma unroll
  for (int j = 0; j < 8; ++j) { f[j] = expf(f[j] - mx); sum += f[j]; }
#pragma unroll
  for (int o = 32; o; o >>= 1) sum += __shfl_xor(sum, o);
  if (lane == 0) rsum[wave] = sum;
  __syncthreads();
  sum = rsum[0] + rsum[1] + rsum[2] + rsum[3];
  const float inv = 1.0f / sum;
  union { bf16 h[8]; uint4 u; } pk;
#pragma unroll
  for (int j = 0; j < 8; ++j) pk.h[j] = __float2bfloat16(f[j] * inv);
  ((uint4*)rp)[threadIdx.x] = pk.u;
}

// ---------------------------------------------------------------------------
// Tiled transpose + convert to bf16: out[c*ldOut + r] = in[r*ldIn + c]
// ---------------------------------------------------------------------------
template <typename TI>
__global__ __launch_bounds__(256) void transpose_bf16_kernel(
    const TI* __restrict__ in, bf16* __restrict__ out,
    int ldIn, int ldOut, long inBatch, long outBatch)
{
  __shared__ bf16 tile[32][33];
  const long zin  = (long)blockIdx.z * inBatch;
  const long zout = (long)blockIdx.z * outBatch;
  const int c0 = blockIdx.x * 32, r0 = blockIdx.y * 32;
  const int tx = threadIdx.x & 31, ty = threadIdx.x >> 5;  // 32 x 8
#pragma unroll
  for (int i = 0; i < 32; i += 8)
    tile[ty + i][tx] = to_bf16(in[zin + (long)(r0 + ty + i) * ldIn + c0 + tx]);
  __syncthreads();
#pragma unroll
  for (int i = 0; i < 32; i += 8)
    out[zout + (long)(c0 + ty + i) * ldOut + r0 + tx] = tile[tx][ty + i];
}

// concat bq|bk|bv -> bqkv[3072]
__global__ __launch_bounds__(256) void concat3_kernel(
    const float* __restrict__ a, const float* __restrict__ b,
    const float* __restrict__ c, float* __restrict__ o)
{
  const int i = blockIdx.x * 256 + threadIdx.x;
  if (i < DIM) { o[i] = a[i]; o[DIM + i] = b[i]; o[2 * DIM + i] = c[i]; }
}

// ---------------------------------------------------------------------------
extern "C" void kernel_launch(void* const* d_in, const int* in_sizes, int n_in,
                              void* d_out, int out_size, void* d_ws, size_t ws_size,
                              hipStream_t stream) {
  const float* x   = (const float*)d_in[0];
  const float* g1  = (const float*)d_in[1];
  const float* be1 = (const float*)d_in[2];
  const float* g2  = (const float*)d_in[3];
  const float* be2 = (const float*)d_in[4];
  const float* Wq  = (const float*)d_in[5];
  const float* bq  = (const float*)d_in[6];
  const float* Wk  = (const float*)d_in[7];
  const float* bk  = (const float*)d_in[8];
  const float* Wv  = (const float*)d_in[9];
  const float* bv  = (const float*)d_in[10];
  const float* W1  = (const float*)d_in[11];
  const float* b1  = (const float*)d_in[12];
  const float* W2  = (const float*)d_in[13];
  const float* b2  = (const float*)d_in[14];
  float* out = (float*)d_out;

  char* ws = (char*)d_ws;
  bf16* WqkvT = (bf16*)(ws + 0);            // 6 MiB  [3072][1024]
  bf16* W1T   = (bf16*)(ws + (6l << 20));   // 8 MiB  [4096][1024]
  bf16* W2T   = (bf16*)(ws + (14l << 20));  // 8 MiB  [1024][4096]
  float* bqkv = (float*)(ws + (22l << 20)); // 12 KiB
  bf16* h     = (bf16*)(ws + (23l << 20));  // 16 MiB [8192][1024]
  bf16* qkv   = (bf16*)(ws + (39l << 20));  // 48 MiB [8192][3072]
  bf16* vT    = (bf16*)(ws + (87l << 20));  // 16 MiB [4][1024][2048]
  bf16* sc    = (bf16*)(ws + (103l << 20)); // 32 MiB [4][2048][2048] bf16
  bf16* g_act = (bf16*)sc;                  // 64 MiB [8192][4096], sequential reuse

  const dim3 blk(256);

  // weights -> bf16 transposed
  concat3_kernel<<<4, blk, 0, stream>>>(bq, bk, bv, bqkv);
  transpose_bf16_kernel<float><<<dim3(32, 32, 1), blk, 0, stream>>>(
      Wq, WqkvT, DIM, DIM, 0, 0);
  transpose_bf16_kernel<float><<<dim3(32, 32, 1), blk, 0, stream>>>(
      Wk, WqkvT + (long)DIM * DIM, DIM, DIM, 0, 0);
  transpose_bf16_kernel<float><<<dim3(32, 32, 1), blk, 0, stream>>>(
      Wv, WqkvT + 2l * DIM * DIM, DIM, DIM, 0, 0);
  transpose_bf16_kernel<float><<<dim3(128, 32, 1), blk, 0, stream>>>(
      W1, W1T, MLPD, DIM, 0, 0);
  transpose_bf16_kernel<float><<<dim3(32, 128, 1), blk, 0, stream>>>(
      W2, W2T, DIM, MLPD, 0, 0);

  // LN1
  ln_kernel<<<ROWS, blk, 0, stream>>>(x, g1, be1, h);

  // fused QKV: [8192][1024] @ [3072][1024]^T + bqkv -> qkv bf16
  gemm128<0><<<dim3(24, 64, 1), blk, 0, stream>>>(
      h, 0, DIM, WqkvT, 0, DIM, qkv, 0, 3 * DIM,
      bqkv, nullptr, 0, 0, DIM, 1.0f);

  // v slice -> vT per batch
  transpose_bf16_kernel<bf16><<<dim3(32, 64, NB), blk, 0, stream>>>(
      qkv + 2 * DIM, vT, 3 * DIM, SEQ, (long)SEQ * 3 * DIM, (long)DIM * SEQ);

  // scores = q @ k^T * (1/32) -> bf16
  gemm128<5><<<dim3(16, 16, NB), blk, 0, stream>>>(
      qkv, (long)SEQ * 3 * DIM, 3 * DIM, qkv + DIM, (long)SEQ * 3 * DIM, 3 * DIM,
      sc, (long)SEQ * SEQ, SEQ, nullptr, nullptr, 0, 0, DIM, 0.03125f);

  // softmax rows (bf16 in/out, in-place, stride 2048)
  softmax_kernel<<<ROWS, blk, 0, stream>>>(sc);

  // x1 = P @ V + x -> d_out
  gemm128<2><<<dim3(8, 16, NB), blk, 0, stream>>>(
      sc, (long)SEQ * SEQ, SEQ, vT, (long)DIM * SEQ, SEQ,
      out, (long)SEQ * DIM, DIM, nullptr, x, (long)SEQ * DIM, DIM, SEQ, 1.0f);

  // LN2
  ln_kernel<<<ROWS, blk, 0, stream>>>(out, g2, be2, h);

  // MLP1: gelu(h @ W1 + b1) -> g_act bf16
  gemm128<3><<<dim3(32, 64, 1), blk, 0, stream>>>(
      h, 0, DIM, W1T, 0, DIM, g_act, 0, MLPD, b1, nullptr, 0, 0, DIM, 1.0f);

  // MLP2: out = g_act @ W2 + b2 + x1
  gemm128<4><<<dim3(8, 64, 1), blk, 0, stream>>>(
      g_act, 0, MLPD, W2T, 0, MLPD, out, 0, DIM, b2, out, 0, DIM, MLPD, 1.0f);
}

// Round 9
// 382.553 us; speedup vs baseline: 3.6055x; 3.6055x over previous
//
#include <hip/hip_runtime.h>
#include <hip/hip_bf16.h>
#include <math.h>

typedef __bf16 bf16x8 __attribute__((ext_vector_type(8)));
typedef float  f32x4  __attribute__((ext_vector_type(4)));
typedef __hip_bfloat16 bf16;

#define DIM  1024
#define MLPD 4096
#define NB   4
#define SEQ  2048
#define ROWS (NB * SEQ) /* 8192 */

__device__ __forceinline__ void gload_lds16(const void* g, void* l) {
  __builtin_amdgcn_global_load_lds(
      (__attribute__((address_space(1))) void*)(g),
      (__attribute__((address_space(3))) void*)(l), 16, 0, 0);
}

__device__ __forceinline__ void bar() {
  asm volatile("" ::: "memory");
  __builtin_amdgcn_s_barrier();
  asm volatile("" ::: "memory");
}

template <int N>
__device__ __forceinline__ void vmw() {
  asm volatile("s_waitcnt vmcnt(%0)" ::"n"(N) : "memory");
}

__device__ __forceinline__ bf16 to_bf16(float v) { return __float2bfloat16(v); }
__device__ __forceinline__ bf16 to_bf16(bf16 v)  { return v; }

// ---------------------------------------------------------------------------
// 128x128 GEMM, BK=32, 4 waves (2x2), 2x16KiB LDS double-buffer (32 KiB),
// depth-1 prefetch with vmcnt(0)+barrier per tile (r6 schedule).
// __launch_bounds__(256,4): r8 post-mortem — bound 5 forced VGPR to 48 (<64
// needed by acc alone) -> accumulator spill, WRITE_SIZE 73MB->1.16GB, 3.5x
// regression. Bound 4 gives 128-VGPR budget (r6 used 60, no spill); LDS
// still admits up to 5 resident blocks/CU (bound is an allocator floor).
// LDS geometry (r7, HW-verified 0 bank conflicts): per operand 64 row-pairs
// x 128B; 16B slot s = ((row&1)*4 + kchunk) ^ ((row>>1)&7). Read addr folds
// to per-thread base + m*1024. Staging keeps LINEAR gload_lds dests; the
// per-lane global SOURCE applies the inverse swizzle (G21 involution):
// t=wave*128+lane; r2=t>>3; u=(t&7)^(r2&7); row=2*r2+(u>>2); kc=u&3.
// EPI: 0=+bias->bf16 | 2=+resid->fp32 | 3=+bias,gelu->bf16
//      4=+bias+resid->fp32 | 5=*scale->bf16
// Requires: M%128==0, N%128==0, K%64==0 (NT even), gx%8==0, gy%8==0.
// ---------------------------------------------------------------------------
template <int EPI>
__global__ __launch_bounds__(256, 4) void gemm128(
    const bf16* __restrict__ A,  long aBatch, int lda,
    const bf16* __restrict__ Bt, long bBatch, int ldb,
    void* __restrict__ Cout,     long cBatch, int ldc,
    const float* __restrict__ bias,
    const float* __restrict__ resid, long rBatch, int ldr,
    int K, float scale)
{
  __shared__ char smem[2][16384];

  // ---- block swizzle: XCD chunking over 8x8 super-tile order
  const int gx = gridDim.x, gy = gridDim.y;
  const int n = gx * gy * gridDim.z;
  const int f = blockIdx.x + gx * (blockIdx.y + gy * blockIdx.z);
  const int o = (f & 7) * (n >> 3) + (f >> 3);   // bijective, n%8==0
  const int sx = gx >> 3;
  int st = o >> 6;
  const int w = o & 63;
  const int spz = sx * (gy >> 3);
  const int bz = st / spz; st -= bz * spz;
  const int sty = st / sx, stx = st - sty * sx;
  const int by = sty * 8 + (w >> 3), bx = stx * 8 + (w & 7);

  const long rowBase = (long)by * 128;
  const long colBase = (long)bx * 128;
  const long ldaB = (long)lda * 2, ldbB = (long)ldb * 2;
  const char* Ag = (const char*)(A + bz * aBatch + rowBase * lda);
  const char* Bg = (const char*)(Bt + bz * bBatch + colBase * ldb);

  const int tid  = threadIdx.x;
  const int lane = tid & 63;
  const int wave = tid >> 6;
  const int wm = wave >> 1, wn = wave & 1;   // 2x2 wave grid, 64x64 each
  const int fr = lane & 15, fq = lane >> 4;

  // fragment read bases: row-pair geometry, XOR folded into lane constants
  const int fh = fr >> 1;
  const int sA = (((fr & 1) << 2) | fq) ^ fh;
  const int laneRd = fh * 128 + sA * 16;
  const int abase = wm * 4096 + laneRd;
  const int bbase = 8192 + wn * 4096 + laneRd;

  // staging: linear dest, inverse-swizzled per-lane source
  const int t0   = wave * 128 + lane;
  const int r2   = t0 >> 3;
  const int u0   = (t0 & 7) ^ (r2 & 7);
  const int row0 = r2 * 2 + (u0 >> 2);
  const int kc0  = u0 & 3;
  const char* aSrc0 = Ag + (long)row0 * ldaB + kc0 * 16;
  const char* aSrc1 = aSrc0 + 16 * ldaB;   // t0+64 => row+16, same kchunk
  const char* bSrc0 = Bg + (long)row0 * ldbB + kc0 * 16;
  const char* bSrc1 = bSrc0 + 16 * ldbB;
  const int doff = wave * 2048 + lane * 16;

  const int NT = K >> 5;
  f32x4 acc[4][4] = {};

#define STAGE(WB)                                                              \
  do {                                                                         \
    gload_lds16(aSrc0, &smem[WB][doff]);                                       \
    gload_lds16(aSrc1, &smem[WB][doff + 1024]);                                \
    gload_lds16(bSrc0, &smem[WB][8192 + doff]);                                \
    gload_lds16(bSrc1, &smem[WB][8192 + doff + 1024]);                         \
    aSrc0 += 64; aSrc1 += 64; bSrc0 += 64; bSrc1 += 64;                        \
  } while (0)

#define READMM(RB)                                                             \
  do {                                                                         \
    const char* _r = &smem[RB][0];                                             \
    bf16x8 av[4], bv[4];                                                       \
    _Pragma("unroll") for (int m = 0; m < 4; ++m)                              \
      av[m] = *(const bf16x8*)(_r + abase + m * 1024);                         \
    _Pragma("unroll") for (int nn = 0; nn < 4; ++nn)                           \
      bv[nn] = *(const bf16x8*)(_r + bbase + nn * 1024);                       \
    __builtin_amdgcn_s_setprio(1);                                             \
    _Pragma("unroll") for (int m = 0; m < 4; ++m)                              \
      _Pragma("unroll") for (int nn = 0; nn < 4; ++nn)                         \
        acc[m][nn] = __builtin_amdgcn_mfma_f32_16x16x32_bf16(                  \
            av[m], bv[nn], acc[m][nn], 0, 0, 0);                               \
    __builtin_amdgcn_s_setprio(0);                                             \
  } while (0)

  // prologue: tile 0 -> buf0
  STAGE(0);
  vmw<0>(); bar();

  for (int t = 0; t < NT; t += 2) {
    STAGE(1);                   // tile t+1 (NT even => always valid)
    READMM(0);                  // tile t
    vmw<0>(); bar();
    if (t + 2 < NT) STAGE(0);   // tile t+2
    READMM(1);                  // tile t+1
    vmw<0>(); bar();
  }

#undef STAGE
#undef READMM

  // Epilogue (C/D mapping: col = ..+fr, row = ..+fq*4+e) — r1-verified
#pragma unroll
  for (int m = 0; m < 4; ++m) {
#pragma unroll
    for (int nn = 0; nn < 4; ++nn) {
      const long col = colBase + wn * 64 + nn * 16 + fr;
#pragma unroll
      for (int e = 0; e < 4; ++e) {
        const long r = rowBase + wm * 64 + m * 16 + fq * 4 + e;
        float v = acc[m][nn][e];
        if constexpr (EPI == 0) {
          v += bias[col];
          ((bf16*)Cout)[bz * cBatch + r * ldc + col] = __float2bfloat16(v);
        } else if constexpr (EPI == 2) {
          v += resid[bz * rBatch + r * ldr + col];
          ((float*)Cout)[bz * cBatch + r * ldc + col] = v;
        } else if constexpr (EPI == 3) {
          v += bias[col];
          const float gl = 0.5f * v * (1.0f + erff(v * 0.70710678118654752f));
          ((bf16*)Cout)[bz * cBatch + r * ldc + col] = __float2bfloat16(gl);
        } else if constexpr (EPI == 4) {
          v += bias[col] + resid[r * (long)ldr + col];
          ((float*)Cout)[bz * cBatch + r * ldc + col] = v;
        } else {  // 5
          ((bf16*)Cout)[bz * cBatch + r * ldc + col] = __float2bfloat16(v * scale);
        }
      }
    }
  }
}

// ---------------------------------------------------------------------------
// LayerNorm over DIM=1024, one block per row, fp32 in -> bf16 out
// ---------------------------------------------------------------------------
__global__ __launch_bounds__(256) void ln_kernel(
    const float* __restrict__ x, const float* __restrict__ gamma,
    const float* __restrict__ beta, bf16* __restrict__ out)
{
  const long row = blockIdx.x;
  const float4 v = ((const float4*)(x + row * DIM))[threadIdx.x];
  float s  = v.x + v.y + v.z + v.w;
  float ss = v.x * v.x + v.y * v.y + v.z * v.z + v.w * v.w;
  const int lane = threadIdx.x & 63, wave = threadIdx.x >> 6;
#pragma unroll
  for (int o = 32; o; o >>= 1) { s += __shfl_xor(s, o); ss += __shfl_xor(ss, o); }
  __shared__ float rs[4], rss[4];
  if (lane == 0) { rs[wave] = s; rss[wave] = ss; }
  __syncthreads();
  s  = rs[0] + rs[1] + rs[2] + rs[3];
  ss = rss[0] + rss[1] + rss[2] + rss[3];
  const float mean = s * (1.0f / DIM);
  const float var  = ss * (1.0f / DIM) - mean * mean;
  const float rstd = rsqrtf(var + 1e-5f);
  const float4 g = ((const float4*)gamma)[threadIdx.x];
  const float4 b = ((const float4*)beta)[threadIdx.x];
  union { bf16 h[4]; uint2 u; } pk;
  pk.h[0] = __float2bfloat16(g.x * (v.x - mean) * rstd + b.x);
  pk.h[1] = __float2bfloat16(g.y * (v.y - mean) * rstd + b.y);
  pk.h[2] = __float2bfloat16(g.z * (v.z - mean) * rstd + b.z);
  pk.h[3] = __float2bfloat16(g.w * (v.w - mean) * rstd + b.w);
  ((uint2*)(out + row * DIM))[threadIdx.x] = pk.u;
}

// ---------------------------------------------------------------------------
// Row softmax over SEQ=2048 bf16 scores, in-place bf16 out (row stride SEQ)
// ---------------------------------------------------------------------------
__global__ __launch_bounds__(256) void softmax_kernel(bf16* __restrict__ scores)
{
  const long row = blockIdx.x;
  bf16* rp = scores + row * (long)SEQ;
  union { bf16 h[8]; uint4 u; } in;
  in.u = ((const uint4*)rp)[threadIdx.x];
  float f[8];
#pragma unroll
  for (int j = 0; j < 8; ++j) f[j] = __bfloat162float(in.h[j]);
  const int lane = threadIdx.x & 63, wave = threadIdx.x >> 6;
  float mx = f[0];
#pragma unroll
  for (int j = 1; j < 8; ++j) mx = fmaxf(mx, f[j]);
#pragma unroll
  for (int o = 32; o; o >>= 1) mx = fmaxf(mx, __shfl_xor(mx, o));
  __shared__ float rm[4], rsum[4];
  if (lane == 0) rm[wave] = mx;
  __syncthreads();
  mx = fmaxf(fmaxf(rm[0], rm[1]), fmaxf(rm[2], rm[3]));
  float sum = 0.0f;
#pragma unroll
  for (int j = 0; j < 8; ++j) { f[j] = expf(f[j] - mx); sum += f[j]; }
#pragma unroll
  for (int o = 32; o; o >>= 1) sum += __shfl_xor(sum, o);
  if (lane == 0) rsum[wave] = sum;
  __syncthreads();
  sum = rsum[0] + rsum[1] + rsum[2] + rsum[3];
  const float inv = 1.0f / sum;
  union { bf16 h[8]; uint4 u; } pk;
#pragma unroll
  for (int j = 0; j < 8; ++j) pk.h[j] = __float2bfloat16(f[j] * inv);
  ((uint4*)rp)[threadIdx.x] = pk.u;
}

// ---------------------------------------------------------------------------
// Tiled transpose + convert to bf16: out[c*ldOut + r] = in[r*ldIn + c]
// ---------------------------------------------------------------------------
template <typename TI>
__global__ __launch_bounds__(256) void transpose_bf16_kernel(
    const TI* __restrict__ in, bf16* __restrict__ out,
    int ldIn, int ldOut, long inBatch, long outBatch)
{
  __shared__ bf16 tile[32][33];
  const long zin  = (long)blockIdx.z * inBatch;
  const long zout = (long)blockIdx.z * outBatch;
  const int c0 = blockIdx.x * 32, r0 = blockIdx.y * 32;
  const int tx = threadIdx.x & 31, ty = threadIdx.x >> 5;  // 32 x 8
#pragma unroll
  for (int i = 0; i < 32; i += 8)
    tile[ty + i][tx] = to_bf16(in[zin + (long)(r0 + ty + i) * ldIn + c0 + tx]);
  __syncthreads();
#pragma unroll
  for (int i = 0; i < 32; i += 8)
    out[zout + (long)(c0 + ty + i) * ldOut + r0 + tx] = tile[tx][ty + i];
}

// concat bq|bk|bv -> bqkv[3072]
__global__ __launch_bounds__(256) void concat3_kernel(
    const float* __restrict__ a, const float* __restrict__ b,
    const float* __restrict__ c, float* __restrict__ o)
{
  const int i = blockIdx.x * 256 + threadIdx.x;
  if (i < DIM) { o[i] = a[i]; o[DIM + i] = b[i]; o[2 * DIM + i] = c[i]; }
}

// ---------------------------------------------------------------------------
extern "C" void kernel_launch(void* const* d_in, const int* in_sizes, int n_in,
                              void* d_out, int out_size, void* d_ws, size_t ws_size,
                              hipStream_t stream) {
  const float* x   = (const float*)d_in[0];
  const float* g1  = (const float*)d_in[1];
  const float* be1 = (const float*)d_in[2];
  const float* g2  = (const float*)d_in[3];
  const float* be2 = (const float*)d_in[4];
  const float* Wq  = (const float*)d_in[5];
  const float* bq  = (const float*)d_in[6];
  const float* Wk  = (const float*)d_in[7];
  const float* bk  = (const float*)d_in[8];
  const float* Wv  = (const float*)d_in[9];
  const float* bv  = (const float*)d_in[10];
  const float* W1  = (const float*)d_in[11];
  const float* b1  = (const float*)d_in[12];
  const float* W2  = (const float*)d_in[13];
  const float* b2  = (const float*)d_in[14];
  float* out = (float*)d_out;

  char* ws = (char*)d_ws;
  bf16* WqkvT = (bf16*)(ws + 0);            // 6 MiB  [3072][1024]
  bf16* W1T   = (bf16*)(ws + (6l << 20));   // 8 MiB  [4096][1024]
  bf16* W2T   = (bf16*)(ws + (14l << 20));  // 8 MiB  [1024][4096]
  float* bqkv = (float*)(ws + (22l << 20)); // 12 KiB
  bf16* h     = (bf16*)(ws + (23l << 20));  // 16 MiB [8192][1024]
  bf16* qkv   = (bf16*)(ws + (39l << 20));  // 48 MiB [8192][3072]
  bf16* vT    = (bf16*)(ws + (87l << 20));  // 16 MiB [4][1024][2048]
  bf16* sc    = (bf16*)(ws + (103l << 20)); // 32 MiB [4][2048][2048] bf16
  bf16* g_act = (bf16*)sc;                  // 64 MiB [8192][4096], sequential reuse

  const dim3 blk(256);

  // weights -> bf16 transposed
  concat3_kernel<<<4, blk, 0, stream>>>(bq, bk, bv, bqkv);
  transpose_bf16_kernel<float><<<dim3(32, 32, 1), blk, 0, stream>>>(
      Wq, WqkvT, DIM, DIM, 0, 0);
  transpose_bf16_kernel<float><<<dim3(32, 32, 1), blk, 0, stream>>>(
      Wk, WqkvT + (long)DIM * DIM, DIM, DIM, 0, 0);
  transpose_bf16_kernel<float><<<dim3(32, 32, 1), blk, 0, stream>>>(
      Wv, WqkvT + 2l * DIM * DIM, DIM, DIM, 0, 0);
  transpose_bf16_kernel<float><<<dim3(128, 32, 1), blk, 0, stream>>>(
      W1, W1T, MLPD, DIM, 0, 0);
  transpose_bf16_kernel<float><<<dim3(32, 128, 1), blk, 0, stream>>>(
      W2, W2T, DIM, MLPD, 0, 0);

  // LN1
  ln_kernel<<<ROWS, blk, 0, stream>>>(x, g1, be1, h);

  // fused QKV: [8192][1024] @ [3072][1024]^T + bqkv -> qkv bf16
  gemm128<0><<<dim3(24, 64, 1), blk, 0, stream>>>(
      h, 0, DIM, WqkvT, 0, DIM, qkv, 0, 3 * DIM,
      bqkv, nullptr, 0, 0, DIM, 1.0f);

  // v slice -> vT per batch
  transpose_bf16_kernel<bf16><<<dim3(32, 64, NB), blk, 0, stream>>>(
      qkv + 2 * DIM, vT, 3 * DIM, SEQ, (long)SEQ * 3 * DIM, (long)DIM * SEQ);

  // scores = q @ k^T * (1/32) -> bf16
  gemm128<5><<<dim3(16, 16, NB), blk, 0, stream>>>(
      qkv, (long)SEQ * 3 * DIM, 3 * DIM, qkv + DIM, (long)SEQ * 3 * DIM, 3 * DIM,
      sc, (long)SEQ * SEQ, SEQ, nullptr, nullptr, 0, 0, DIM, 0.03125f);

  // softmax rows (bf16 in/out, in-place, stride 2048)
  softmax_kernel<<<ROWS, blk, 0, stream>>>(sc);

  // x1 = P @ V + x -> d_out
  gemm128<2><<<dim3(8, 16, NB), blk, 0, stream>>>(
      sc, (long)SEQ * SEQ, SEQ, vT, (long)DIM * SEQ, SEQ,
      out, (long)SEQ * DIM, DIM, nullptr, x, (long)SEQ * DIM, DIM, SEQ, 1.0f);

  // LN2
  ln_kernel<<<ROWS, blk, 0, stream>>>(out, g2, be2, h);

  // MLP1: gelu(h @ W1 + b1) -> g_act bf16
  gemm128<3><<<dim3(32, 64, 1), blk, 0, stream>>>(
      h, 0, DIM, W1T, 0, DIM, g_act, 0, MLPD, b1, nullptr, 0, 0, DIM, 1.0f);

  // MLP2: out = g_act @ W2 + b2 + x1
  gemm128<4><<<dim3(8, 64, 1), blk, 0, stream>>>(
      g_act, 0, MLPD, W2T, 0, MLPD, out, 0, DIM, b2, out, 0, DIM, MLPD, 1.0f);
}

// Round 10
// 372.938 us; speedup vs baseline: 3.6984x; 1.0258x over previous
//
#include <hip/hip_runtime.h>
#include <hip/hip_bf16.h>
#include <math.h>

typedef __bf16 bf16x8 __attribute__((ext_vector_type(8)));
typedef float  f32x4  __attribute__((ext_vector_type(4)));
typedef __hip_bfloat16 bf16;

#define DIM  1024
#define MLPD 4096
#define NB   4
#define SEQ  2048
#define ROWS (NB * SEQ) /* 8192 */

__device__ __forceinline__ void gload_lds16(const void* g, void* l) {
  __builtin_amdgcn_global_load_lds(
      (__attribute__((address_space(1))) void*)(g),
      (__attribute__((address_space(3))) void*)(l), 16, 0, 0);
}

__device__ __forceinline__ void bar() {
  asm volatile("" ::: "memory");
  __builtin_amdgcn_s_barrier();
  asm volatile("" ::: "memory");
}

__device__ __forceinline__ void vm0() {
  asm volatile("s_waitcnt vmcnt(0)" ::: "memory");
}

__device__ __forceinline__ bf16 to_bf16(float v) { return __float2bfloat16(v); }
__device__ __forceinline__ bf16 to_bf16(bf16 v)  { return v; }

// exact-GELU via A&S 7.1.26 erf approximation (max abs err ~1.5e-7 + rcp/exp
// approx ~1e-6 total — far inside the 0.09 absmax headroom). ~12 VALU + exp
// vs libm erff's ~30: the r9 counters showed 64 erff/thread dominated MLP1's
// epilogue VALU (~2300 inst/wave/block).
__device__ __forceinline__ float gelu_exact_fast(float v) {
  const float x  = v * 0.70710678118654752f;
  const float ax = fabsf(x);
  const float t  = __builtin_amdgcn_rcpf(1.0f + 0.3275911f * ax);
  const float p  = t * (0.254829592f +
                   t * (-0.284496736f +
                   t * (1.421413741f +
                   t * (-1.453152027f + t * 1.061405429f))));
  float erf = 1.0f - p * __expf(-x * x);
  erf = copysignf(erf, x);
  return 0.5f * v * (1.0f + erf);
}

// ---------------------------------------------------------------------------
// 128x128 GEMM, BK=32, 4 waves (2x2), 32 KiB LDS as TWO 16 KiB sub-buffers.
// Round-10 schedule: period = 2 K-tiles — {STAGE t->sub0, STAGE t+1->sub1,
// vmcnt(0), bar, READMM(sub0), READMM(sub1), bar}. One drain per 64-K
// (r9 drained per 32-K; r6/r7/r9 all completed one block-tile per ~1200cyc
// regardless of prefetch depth/conflicts -> test barrier-period length).
// No cross-period double buffer: the trailing bar orders reads before the
// next period's stages. 5 blocks/CU (LDS 32K; VGPR ~64 -> not binding).
// LDS geometry (r7, HW-verified 0 bank conflicts): per operand 64 row-pairs
// x 128B; 16B slot s = ((row&1)*4 + kchunk) ^ ((row>>1)&7). Read addr folds
// to per-thread base + m*1024. Staging keeps LINEAR gload_lds dests; the
// per-lane global SOURCE applies the inverse swizzle (G21 involution):
// t=wave*128+lane; r2=t>>3; u=(t&7)^(r2&7); row=2*r2+(u>>2); kc=u&3.
// EPI: 0=+bias->bf16 | 2=+resid->fp32 | 3=+bias,gelu->bf16
//      4=+bias+resid->fp32 | 5=*scale->bf16
// Requires: M%128==0, N%128==0, K%64==0 (NT even), gx%8==0, gy%8==0.
// ---------------------------------------------------------------------------
template <int EPI>
__global__ __launch_bounds__(256, 4) void gemm128(
    const bf16* __restrict__ A,  long aBatch, int lda,
    const bf16* __restrict__ Bt, long bBatch, int ldb,
    void* __restrict__ Cout,     long cBatch, int ldc,
    const float* __restrict__ bias,
    const float* __restrict__ resid, long rBatch, int ldr,
    int K, float scale)
{
  __shared__ char smem[2][16384];

  // ---- block swizzle: XCD chunking over 8x8 super-tile order
  const int gx = gridDim.x, gy = gridDim.y;
  const int n = gx * gy * gridDim.z;
  const int f = blockIdx.x + gx * (blockIdx.y + gy * blockIdx.z);
  const int o = (f & 7) * (n >> 3) + (f >> 3);   // bijective, n%8==0
  const int sx = gx >> 3;
  int st = o >> 6;
  const int w = o & 63;
  const int spz = sx * (gy >> 3);
  const int bz = st / spz; st -= bz * spz;
  const int sty = st / sx, stx = st - sty * sx;
  const int by = sty * 8 + (w >> 3), bx = stx * 8 + (w & 7);

  const long rowBase = (long)by * 128;
  const long colBase = (long)bx * 128;
  const long ldaB = (long)lda * 2, ldbB = (long)ldb * 2;
  const char* Ag = (const char*)(A + bz * aBatch + rowBase * lda);
  const char* Bg = (const char*)(Bt + bz * bBatch + colBase * ldb);

  const int tid  = threadIdx.x;
  const int lane = tid & 63;
  const int wave = tid >> 6;
  const int wm = wave >> 1, wn = wave & 1;   // 2x2 wave grid, 64x64 each
  const int fr = lane & 15, fq = lane >> 4;

  // fragment read bases: row-pair geometry, XOR folded into lane constants
  const int fh = fr >> 1;
  const int sA = (((fr & 1) << 2) | fq) ^ fh;
  const int laneRd = fh * 128 + sA * 16;
  const int abase = wm * 4096 + laneRd;
  const int bbase = 8192 + wn * 4096 + laneRd;

  // staging: linear dest, inverse-swizzled per-lane source
  const int t0   = wave * 128 + lane;
  const int r2   = t0 >> 3;
  const int u0   = (t0 & 7) ^ (r2 & 7);
  const int row0 = r2 * 2 + (u0 >> 2);
  const int kc0  = u0 & 3;
  const char* aSrc0 = Ag + (long)row0 * ldaB + kc0 * 16;
  const char* aSrc1 = aSrc0 + 16 * ldaB;   // t0+64 => row+16, same kchunk
  const char* bSrc0 = Bg + (long)row0 * ldbB + kc0 * 16;
  const char* bSrc1 = bSrc0 + 16 * ldbB;
  const int doff = wave * 2048 + lane * 16;

  const int NT = K >> 5;
  f32x4 acc[4][4] = {};

#define STAGE(WB)                                                              \
  do {                                                                         \
    gload_lds16(aSrc0, &smem[WB][doff]);                                       \
    gload_lds16(aSrc1, &smem[WB][doff + 1024]);                                \
    gload_lds16(bSrc0, &smem[WB][8192 + doff]);                                \
    gload_lds16(bSrc1, &smem[WB][8192 + doff + 1024]);                         \
    aSrc0 += 64; aSrc1 += 64; bSrc0 += 64; bSrc1 += 64;                        \
  } while (0)

#define READMM(RB)                                                             \
  do {                                                                         \
    const char* _r = &smem[RB][0];                                             \
    bf16x8 av[4], bv[4];                                                       \
    _Pragma("unroll") for (int m = 0; m < 4; ++m)                              \
      av[m] = *(const bf16x8*)(_r + abase + m * 1024);                         \
    _Pragma("unroll") for (int nn = 0; nn < 4; ++nn)                           \
      bv[nn] = *(const bf16x8*)(_r + bbase + nn * 1024);                       \
    __builtin_amdgcn_s_setprio(1);                                             \
    _Pragma("unroll") for (int m = 0; m < 4; ++m)                              \
      _Pragma("unroll") for (int nn = 0; nn < 4; ++nn)                         \
        acc[m][nn] = __builtin_amdgcn_mfma_f32_16x16x32_bf16(                  \
            av[m], bv[nn], acc[m][nn], 0, 0, 0);                               \
    __builtin_amdgcn_s_setprio(0);                                             \
  } while (0)

  for (int t = 0; t < NT; t += 2) {
    STAGE(0);                   // tile t   -> sub-buffer 0
    STAGE(1);                   // tile t+1 -> sub-buffer 1 (NT even)
    vm0(); bar();
    READMM(0);
    READMM(1);
    bar();                      // reads done before next period's stages
  }

#undef STAGE
#undef READMM

  // Epilogue (C/D mapping: col = ..+fr, row = ..+fq*4+e) — r1-verified
#pragma unroll
  for (int m = 0; m < 4; ++m) {
#pragma unroll
    for (int nn = 0; nn < 4; ++nn) {
      const long col = colBase + wn * 64 + nn * 16 + fr;
#pragma unroll
      for (int e = 0; e < 4; ++e) {
        const long r = rowBase + wm * 64 + m * 16 + fq * 4 + e;
        float v = acc[m][nn][e];
        if constexpr (EPI == 0) {
          v += bias[col];
          ((bf16*)Cout)[bz * cBatch + r * ldc + col] = __float2bfloat16(v);
        } else if constexpr (EPI == 2) {
          v += resid[bz * rBatch + r * ldr + col];
          ((float*)Cout)[bz * cBatch + r * ldc + col] = v;
        } else if constexpr (EPI == 3) {
          v += bias[col];
          ((bf16*)Cout)[bz * cBatch + r * ldc + col] =
              __float2bfloat16(gelu_exact_fast(v));
        } else if constexpr (EPI == 4) {
          v += bias[col] + resid[r * (long)ldr + col];
          ((float*)Cout)[bz * cBatch + r * ldc + col] = v;
        } else {  // 5
          ((bf16*)Cout)[bz * cBatch + r * ldc + col] = __float2bfloat16(v * scale);
        }
      }
    }
  }
}

// ---------------------------------------------------------------------------
// LayerNorm over DIM=1024, one block per row, fp32 in -> bf16 out
// ---------------------------------------------------------------------------
__global__ __launch_bounds__(256) void ln_kernel(
    const float* __restrict__ x, const float* __restrict__ gamma,
    const float* __restrict__ beta, bf16* __restrict__ out)
{
  const long row = blockIdx.x;
  const float4 v = ((const float4*)(x + row * DIM))[threadIdx.x];
  float s  = v.x + v.y + v.z + v.w;
  float ss = v.x * v.x + v.y * v.y + v.z * v.z + v.w * v.w;
  const int lane = threadIdx.x & 63, wave = threadIdx.x >> 6;
#pragma unroll
  for (int o = 32; o; o >>= 1) { s += __shfl_xor(s, o); ss += __shfl_xor(ss, o); }
  __shared__ float rs[4], rss[4];
  if (lane == 0) { rs[wave] = s; rss[wave] = ss; }
  __syncthreads();
  s  = rs[0] + rs[1] + rs[2] + rs[3];
  ss = rss[0] + rss[1] + rss[2] + rss[3];
  const float mean = s * (1.0f / DIM);
  const float var  = ss * (1.0f / DIM) - mean * mean;
  const float rstd = rsqrtf(var + 1e-5f);
  const float4 g = ((const float4*)gamma)[threadIdx.x];
  const float4 b = ((const float4*)beta)[threadIdx.x];
  union { bf16 h[4]; uint2 u; } pk;
  pk.h[0] = __float2bfloat16(g.x * (v.x - mean) * rstd + b.x);
  pk.h[1] = __float2bfloat16(g.y * (v.y - mean) * rstd + b.y);
  pk.h[2] = __float2bfloat16(g.z * (v.z - mean) * rstd + b.z);
  pk.h[3] = __float2bfloat16(g.w * (v.w - mean) * rstd + b.w);
  ((uint2*)(out + row * DIM))[threadIdx.x] = pk.u;
}

// ---------------------------------------------------------------------------
// Row softmax over SEQ=2048 bf16 scores, in-place bf16 out (row stride SEQ)
// ---------------------------------------------------------------------------
__global__ __launch_bounds__(256) void softmax_kernel(bf16* __restrict__ scores)
{
  const long row = blockIdx.x;
  bf16* rp = scores + row * (long)SEQ;
  union { bf16 h[8]; uint4 u; } in;
  in.u = ((const uint4*)rp)[threadIdx.x];
  float f[8];
#pragma unroll
  for (int j = 0; j < 8; ++j) f[j] = __bfloat162float(in.h[j]);
  const int lane = threadIdx.x & 63, wave = threadIdx.x >> 6;
  float mx = f[0];
#pragma unroll
  for (int j = 1; j < 8; ++j) mx = fmaxf(mx, f[j]);
#pragma unroll
  for (int o = 32; o; o >>= 1) mx = fmaxf(mx, __shfl_xor(mx, o));
  __shared__ float rm[4], rsum[4];
  if (lane == 0) rm[wave] = mx;
  __syncthreads();
  mx = fmaxf(fmaxf(rm[0], rm[1]), fmaxf(rm[2], rm[3]));
  float sum = 0.0f;
#pragma unroll
  for (int j = 0; j < 8; ++j) { f[j] = expf(f[j] - mx); sum += f[j]; }
#pragma unroll
  for (int o = 32; o; o >>= 1) sum += __shfl_xor(sum, o);
  if (lane == 0) rsum[wave] = sum;
  __syncthreads();
  sum = rsum[0] + rsum[1] + rsum[2] + rsum[3];
  const float inv = 1.0f / sum;
  union { bf16 h[8]; uint4 u; } pk;
#pragma unroll
  for (int j = 0; j < 8; ++j) pk.h[j] = __float2bfloat16(f[j] * inv);
  ((uint4*)rp)[threadIdx.x] = pk.u;
}

// ---------------------------------------------------------------------------
// Tiled transpose + convert to bf16: out[c*ldOut + r] = in[r*ldIn + c]
// ---------------------------------------------------------------------------
template <typename TI>
__global__ __launch_bounds__(256) void transpose_bf16_kernel(
    const TI* __restrict__ in, bf16* __restrict__ out,
    int ldIn, int ldOut, long inBatch, long outBatch)
{
  __shared__ bf16 tile[32][33];
  const long zin  = (long)blockIdx.z * inBatch;
  const long zout = (long)blockIdx.z * outBatch;
  const int c0 = blockIdx.x * 32, r0 = blockIdx.y * 32;
  const int tx = threadIdx.x & 31, ty = threadIdx.x >> 5;  // 32 x 8
#pragma unroll
  for (int i = 0; i < 32; i += 8)
    tile[ty + i][tx] = to_bf16(in[zin + (long)(r0 + ty + i) * ldIn + c0 + tx]);
  __syncthreads();
#pragma unroll
  for (int i = 0; i < 32; i += 8)
    out[zout + (long)(c0 + ty + i) * ldOut + r0 + tx] = tile[tx][ty + i];
}

// concat bq|bk|bv -> bqkv[3072]
__global__ __launch_bounds__(256) void concat3_kernel(
    const float* __restrict__ a, const float* __restrict__ b,
    const float* __restrict__ c, float* __restrict__ o)
{
  const int i = blockIdx.x * 256 + threadIdx.x;
  if (i < DIM) { o[i] = a[i]; o[DIM + i] = b[i]; o[2 * DIM + i] = c[i]; }
}

// ---------------------------------------------------------------------------
extern "C" void kernel_launch(void* const* d_in, const int* in_sizes, int n_in,
                              void* d_out, int out_size, void* d_ws, size_t ws_size,
                              hipStream_t stream) {
  const float* x   = (const float*)d_in[0];
  const float* g1  = (const float*)d_in[1];
  const float* be1 = (const float*)d_in[2];
  const float* g2  = (const float*)d_in[3];
  const float* be2 = (const float*)d_in[4];
  const float* Wq  = (const float*)d_in[5];
  const float* bq  = (const float*)d_in[6];
  const float* Wk  = (const float*)d_in[7];
  const float* bk  = (const float*)d_in[8];
  const float* Wv  = (const float*)d_in[9];
  const float* bv  = (const float*)d_in[10];
  const float* W1  = (const float*)d_in[11];
  const float* b1  = (const float*)d_in[12];
  const float* W2  = (const float*)d_in[13];
  const float* b2  = (const float*)d_in[14];
  float* out = (float*)d_out;

  char* ws = (char*)d_ws;
  bf16* WqkvT = (bf16*)(ws + 0);            // 6 MiB  [3072][1024]
  bf16* W1T   = (bf16*)(ws + (6l << 20));   // 8 MiB  [4096][1024]
  bf16* W2T   = (bf16*)(ws + (14l << 20));  // 8 MiB  [1024][4096]
  float* bqkv = (float*)(ws + (22l << 20)); // 12 KiB
  bf16* h     = (bf16*)(ws + (23l << 20));  // 16 MiB [8192][1024]
  bf16* qkv   = (bf16*)(ws + (39l << 20));  // 48 MiB [8192][3072]
  bf16* vT    = (bf16*)(ws + (87l << 20));  // 16 MiB [4][1024][2048]
  bf16* sc    = (bf16*)(ws + (103l << 20)); // 32 MiB [4][2048][2048] bf16
  bf16* g_act = (bf16*)sc;                  // 64 MiB [8192][4096], sequential reuse

  const dim3 blk(256);

  // weights -> bf16 transposed
  concat3_kernel<<<4, blk, 0, stream>>>(bq, bk, bv, bqkv);
  transpose_bf16_kernel<float><<<dim3(32, 32, 1), blk, 0, stream>>>(
      Wq, WqkvT, DIM, DIM, 0, 0);
  transpose_bf16_kernel<float><<<dim3(32, 32, 1), blk, 0, stream>>>(
      Wk, WqkvT + (long)DIM * DIM, DIM, DIM, 0, 0);
  transpose_bf16_kernel<float><<<dim3(32, 32, 1), blk, 0, stream>>>(
      Wv, WqkvT + 2l * DIM * DIM, DIM, DIM, 0, 0);
  transpose_bf16_kernel<float><<<dim3(128, 32, 1), blk, 0, stream>>>(
      W1, W1T, MLPD, DIM, 0, 0);
  transpose_bf16_kernel<float><<<dim3(32, 128, 1), blk, 0, stream>>>(
      W2, W2T, DIM, MLPD, 0, 0);

  // LN1
  ln_kernel<<<ROWS, blk, 0, stream>>>(x, g1, be1, h);

  // fused QKV: [8192][1024] @ [3072][1024]^T + bqkv -> qkv bf16
  gemm128<0><<<dim3(24, 64, 1), blk, 0, stream>>>(
      h, 0, DIM, WqkvT, 0, DIM, qkv, 0, 3 * DIM,
      bqkv, nullptr, 0, 0, DIM, 1.0f);

  // v slice -> vT per batch
  transpose_bf16_kernel<bf16><<<dim3(32, 64, NB), blk, 0, stream>>>(
      qkv + 2 * DIM, vT, 3 * DIM, SEQ, (long)SEQ * 3 * DIM, (long)DIM * SEQ);

  // scores = q @ k^T * (1/32) -> bf16
  gemm128<5><<<dim3(16, 16, NB), blk, 0, stream>>>(
      qkv, (long)SEQ * 3 * DIM, 3 * DIM, qkv + DIM, (long)SEQ * 3 * DIM, 3 * DIM,
      sc, (long)SEQ * SEQ, SEQ, nullptr, nullptr, 0, 0, DIM, 0.03125f);

  // softmax rows (bf16 in/out, in-place, stride 2048)
  softmax_kernel<<<ROWS, blk, 0, stream>>>(sc);

  // x1 = P @ V + x -> d_out
  gemm128<2><<<dim3(8, 16, NB), blk, 0, stream>>>(
      sc, (long)SEQ * SEQ, SEQ, vT, (long)DIM * SEQ, SEQ,
      out, (long)SEQ * DIM, DIM, nullptr, x, (long)SEQ * DIM, DIM, SEQ, 1.0f);

  // LN2
  ln_kernel<<<ROWS, blk, 0, stream>>>(out, g2, be2, h);

  // MLP1: gelu(h @ W1 + b1) -> g_act bf16
  gemm128<3><<<dim3(32, 64, 1), blk, 0, stream>>>(
      h, 0, DIM, W1T, 0, DIM, g_act, 0, MLPD, b1, nullptr, 0, 0, DIM, 1.0f);

  // MLP2: out = g_act @ W2 + b2 + x1
  gemm128<4><<<dim3(8, 64, 1), blk, 0, stream>>>(
      g_act, 0, MLPD, W2T, 0, MLPD, out, 0, DIM, b2, out, 0, DIM, MLPD, 1.0f);
}